// Round 2
// baseline (1306.323 us; speedup 1.0000x reference)
//
#include <hip/hip_runtime.h>
#include <hip/hip_bf16.h>

// GPT forward: L=4, B=2, S=1024, D=768, H=12, DK=64, DI=3072, V=512
// Strategy: f32 residual stream, bf16 MFMA GEMMs (16x16x32), flash attention.

#define TKN    2048   // B*S
#define DMODEL 768
#define SEQ    1024
#define NH     12
#define DHEAD  64
#define DFF    3072
#define NL     4
#define NVOCAB 512

typedef unsigned short u16;
typedef __attribute__((ext_vector_type(4))) float f32x4;
typedef __attribute__((ext_vector_type(8))) short short8;
typedef __attribute__((ext_vector_type(4))) unsigned short us4;
typedef __attribute__((ext_vector_type(4))) unsigned int u32x4;

__device__ __forceinline__ u16 f2bf(float f) {
  unsigned u = __builtin_bit_cast(unsigned, f);
  u += 0x7fffu + ((u >> 16) & 1u);   // RNE
  return (u16)(u >> 16);
}

__device__ __forceinline__ short8 mk8(us4 lo, us4 hi) {
  short8 r;
  r[0] = (short)lo[0]; r[1] = (short)lo[1]; r[2] = (short)lo[2]; r[3] = (short)lo[3];
  r[4] = (short)hi[0]; r[5] = (short)hi[1]; r[6] = (short)hi[2]; r[7] = (short)hi[3];
  return r;
}

// ---------------- embedding: h[t,:] = embed[x[t],:] + pos[s,:] ----------------
__global__ __launch_bounds__(256) void k_embed(const int* __restrict__ x,
                                               const float* __restrict__ emb,
                                               const float* __restrict__ pos,
                                               float* __restrict__ h) {
  int t = blockIdx.x;
  int s = t & (SEQ - 1);
  int id = x[t];
  int d = threadIdx.x;
#pragma unroll
  for (int j = 0; j < 3; ++j, d += 256)
    h[t * DMODEL + d] = emb[id * DMODEL + d] + pos[s * DMODEL + d];
}

// ---------------- layernorm (f32 in -> bf16 out), one block per row ----------------
__global__ __launch_bounds__(256) void k_ln(const float* __restrict__ h,
                                            const float* __restrict__ gam,
                                            const float* __restrict__ bet,
                                            u16* __restrict__ out) {
  __shared__ float sbuf[8];
  int row = blockIdx.x, tid = threadIdx.x;
  const float* hr = h + (size_t)row * DMODEL;
  float x0 = hr[tid], x1 = hr[tid + 256], x2 = hr[tid + 512];
  float s = x0 + x1 + x2;
#pragma unroll
  for (int off = 32; off > 0; off >>= 1) s += __shfl_down(s, off);
  if ((tid & 63) == 0) sbuf[tid >> 6] = s;
  __syncthreads();
  float mu = (sbuf[0] + sbuf[1] + sbuf[2] + sbuf[3]) * (1.0f / DMODEL);
  float d0 = x0 - mu, d1 = x1 - mu, d2 = x2 - mu;
  float v = d0 * d0 + d1 * d1 + d2 * d2;
#pragma unroll
  for (int off = 32; off > 0; off >>= 1) v += __shfl_down(v, off);
  if ((tid & 63) == 0) sbuf[4 + (tid >> 6)] = v;
  __syncthreads();
  float var = (sbuf[4] + sbuf[5] + sbuf[6] + sbuf[7]) * (1.0f / DMODEL);
  float rstd = rsqrtf(var + 1e-5f);
  size_t o = (size_t)row * DMODEL;
  out[o + tid]       = f2bf(d0 * rstd * gam[tid]       + bet[tid]);
  out[o + tid + 256] = f2bf(d1 * rstd * gam[tid + 256] + bet[tid + 256]);
  out[o + tid + 512] = f2bf(d2 * rstd * gam[tid + 512] + bet[tid + 512]);
}

// ---------------- GEMM: C[M,N] = A[M,K](bf16) * B[K,N](f32 weights) ----------------
// EP 0: out bf16 = acc + bias           (QKV proj)
// EP 1: out f32 += acc + bias           (residual RMW: O proj, MLP out)
// EP 2: out bf16 = gelu(acc + bias)     (MLP in)
// EP 3: out f32 = acc                   (logits, no bias)
#define BM 128
#define BN 64
#define BK 32
#define LDA 40
#define LDB 40

template <int EP>
__global__ __launch_bounds__(256) void k_gemm(const u16* __restrict__ A,
                                              const float* __restrict__ B,
                                              const float* __restrict__ bias,
                                              void* __restrict__ outp,
                                              int N, int K) {
  __shared__ u16 As[BM * LDA];
  __shared__ u16 Bs[BN * LDB];   // transposed: Bs[n][k]
  const int bn = blockIdx.x * BN, bm = blockIdx.y * BM;
  const int tid = threadIdx.x;
  const int lane = tid & 63, wid = tid >> 6;
  const int g = lane >> 4, fl = lane & 15;
  const int wm = wid >> 1, wn = wid & 1;
  const int ar = tid >> 1, ac = (tid & 1) << 4;   // A stage: row, col base (16 elems/thread)
  const int br = tid >> 3, bc = (tid & 7) << 3;   // B stage: k-row, n base

  f32x4 acc[4][2] = {};

  for (int kk = 0; kk < K; kk += BK) {
    // ---- stage A tile [BM][BK] bf16: each thread 2x16B = 16 elems ----
    const u16* ap = A + (size_t)(bm + ar) * K + kk + ac;
    u32x4 av0 = *(const u32x4*)(ap);
    u32x4 av1 = *(const u32x4*)(ap + 8);
    // ---- stage B tile [BK][BN] f32 -> bf16, transposed into Bs[n][k] ----
    const float* bp = B + (size_t)(kk + br) * N + bn + bc;
    float4 b0 = *(const float4*)bp;
    float4 b1 = *(const float4*)(bp + 4);
    *(u32x4*)(As + ar * LDA + ac) = av0;
    *(u32x4*)(As + ar * LDA + ac + 8) = av1;
    Bs[(bc + 0) * LDB + br] = f2bf(b0.x);
    Bs[(bc + 1) * LDB + br] = f2bf(b0.y);
    Bs[(bc + 2) * LDB + br] = f2bf(b0.z);
    Bs[(bc + 3) * LDB + br] = f2bf(b0.w);
    Bs[(bc + 4) * LDB + br] = f2bf(b1.x);
    Bs[(bc + 5) * LDB + br] = f2bf(b1.y);
    Bs[(bc + 6) * LDB + br] = f2bf(b1.z);
    Bs[(bc + 7) * LDB + br] = f2bf(b1.w);
    __syncthreads();

    short8 af[4], bfrag[2];
#pragma unroll
    for (int i = 0; i < 4; ++i) {
      int row = wm * 64 + i * 16 + fl;
      us4 lo = *(const us4*)(As + row * LDA + 4 * g);
      us4 hi = *(const us4*)(As + row * LDA + 16 + 4 * g);
      af[i] = mk8(lo, hi);
    }
#pragma unroll
    for (int j = 0; j < 2; ++j) {
      int col = wn * 32 + j * 16 + fl;
      us4 lo = *(const us4*)(Bs + col * LDB + 4 * g);
      us4 hi = *(const us4*)(Bs + col * LDB + 16 + 4 * g);
      bfrag[j] = mk8(lo, hi);
    }
#pragma unroll
    for (int i = 0; i < 4; ++i)
#pragma unroll
      for (int j = 0; j < 2; ++j)
        acc[i][j] = __builtin_amdgcn_mfma_f32_16x16x32_bf16(af[i], bfrag[j], acc[i][j], 0, 0, 0);
    __syncthreads();
  }

  // ---- epilogue ----
  const int row0 = bm + wm * 64 + 4 * g;
  const int col0 = bn + wn * 32 + fl;
#pragma unroll
  for (int j = 0; j < 2; ++j) {
    int col = col0 + j * 16;
    float bv = (EP == 3) ? 0.0f : bias[col];
#pragma unroll
    for (int i = 0; i < 4; ++i) {
#pragma unroll
      for (int r = 0; r < 4; ++r) {
        int row = row0 + i * 16 + r;
        float val = acc[i][j][r] + bv;
        size_t idx = (size_t)row * N + col;
        if (EP == 0) {
          ((u16*)outp)[idx] = f2bf(val);
        } else if (EP == 1) {
          ((float*)outp)[idx] += val;
        } else if (EP == 2) {
          float t = 0.7978845608028654f * (val + 0.044715f * val * val * val);
          ((u16*)outp)[idx] = f2bf(0.5f * val * (1.0f + tanhf(t)));
        } else {
          ((float*)outp)[idx] = val;
        }
      }
    }
  }
}

// ---------------- flash attention ----------------
// grid: (S/64, B*H). 4 waves/block, wave w owns q rows [qb*64+w*16, +16).
// Swapped QK^T: S^T = mfma(K_frag, Q_frag) so lane holds S[q=lane&15][key=kb+4g+r].
__global__ __launch_bounds__(256) void k_attn(const u16* __restrict__ Q,
                                              const u16* __restrict__ K,
                                              const u16* __restrict__ V,
                                              u16* __restrict__ O) {
  __shared__ u16 Vt[DHEAD * 68];   // transposed V tile: Vt[d][key(64)]
  const int qb = blockIdx.x;
  const int bh = blockIdx.y;
  const int b = bh / NH, hh = bh % NH;
  const int tid = threadIdx.x, lane = tid & 63, w = tid >> 6;
  const int g = lane >> 4, fl = lane & 15;
  const int qrow = qb * 64 + w * 16 + fl;     // this lane's q (B-operand col)
  const u16* qp = Q + (size_t)(b * SEQ + qrow) * DMODEL + hh * DHEAD;

  short8 qf[2];
#pragma unroll
  for (int hf = 0; hf < 2; ++hf) {
    us4 lo = *(const us4*)(qp + hf * 32 + 4 * g);
    us4 hi = *(const us4*)(qp + hf * 32 + 16 + 4 * g);
    qf[hf] = mk8(lo, hi);
  }

  float m = -1e30f, lsum = 0.0f;
  f32x4 oacc[4] = {};
  const int qmaxw = qb * 64 + w * 16 + 15;
  const int vr = tid >> 2, vd = (tid & 3) << 4;   // V staging: key row, d base

  for (int t64 = 0; t64 <= qb; ++t64) {
    // stage V[t64*64 .. +63][hh*64 .. +63] transposed into Vt
    const u16* vp = V + (size_t)(b * SEQ + t64 * 64 + vr) * DMODEL + hh * DHEAD + vd;
#pragma unroll
    for (int qi = 0; qi < 4; ++qi) {
      us4 vv = *(const us4*)(vp + qi * 4);
#pragma unroll
      for (int i = 0; i < 4; ++i) Vt[(vd + qi * 4 + i) * 68 + vr] = vv[i];
    }
    __syncthreads();

#pragma unroll
    for (int i32 = 0; i32 < 2; ++i32) {
      int kb = t64 * 64 + i32 * 32;
      if (kb <= qmaxw) {
        // S^T frags over 32 keys
        f32x4 sfr[2];
#pragma unroll
        for (int sub = 0; sub < 2; ++sub) {
          const u16* kp = K + (size_t)(b * SEQ + kb + sub * 16 + fl) * DMODEL + hh * DHEAD;
          short8 kf0 = mk8(*(const us4*)(kp + 4 * g), *(const us4*)(kp + 16 + 4 * g));
          short8 kf1 = mk8(*(const us4*)(kp + 32 + 4 * g), *(const us4*)(kp + 48 + 4 * g));
          f32x4 s = {};
          s = __builtin_amdgcn_mfma_f32_16x16x32_bf16(kf0, qf[0], s, 0, 0, 0);
          s = __builtin_amdgcn_mfma_f32_16x16x32_bf16(kf1, qf[1], s, 0, 0, 0);
          sfr[sub] = s;
        }
        // scale + causal mask; lane holds keys kb + sub*16 + 4g + r for q=fl
        float sc[8];
#pragma unroll
        for (int sub = 0; sub < 2; ++sub)
#pragma unroll
          for (int r = 0; r < 4; ++r) {
            int key = kb + sub * 16 + 4 * g + r;
            float sv = sfr[sub][r] * 0.125f;
            sc[sub * 4 + r] = (key <= qrow) ? sv : -1e30f;
          }
        // online softmax (row = q = fl; reduce across g via xor 16,32)
        float pmax = sc[0];
#pragma unroll
        for (int e = 1; e < 8; ++e) pmax = fmaxf(pmax, sc[e]);
        pmax = fmaxf(pmax, __shfl_xor(pmax, 16));
        pmax = fmaxf(pmax, __shfl_xor(pmax, 32));
        float mnew = fmaxf(m, pmax);
        float corr = __expf(m - mnew);
        float p[8], ps = 0.0f;
#pragma unroll
        for (int e = 0; e < 8; ++e) { p[e] = __expf(sc[e] - mnew); ps += p[e]; }
        ps += __shfl_xor(ps, 16);
        ps += __shfl_xor(ps, 32);
        lsum = lsum * corr + ps;
        m = mnew;
        // rescale O accum: need corr for q = 4g+r (C-layout rows)
        float cr[4];
#pragma unroll
        for (int r = 0; r < 4; ++r) cr[r] = __shfl(corr, 4 * g + r);
#pragma unroll
        for (int nb = 0; nb < 4; ++nb)
#pragma unroll
          for (int r = 0; r < 4; ++r) oacc[nb][r] *= cr[r];
        // P frag (A-operand): elem e -> key kb + 16*(e>>2) + 4g + (e&3)
        short8 pf;
#pragma unroll
        for (int e = 0; e < 8; ++e) pf[e] = (short)f2bf(p[e]);
        // PV: O[q][d] += P * V
#pragma unroll
        for (int nb = 0; nb < 4; ++nb) {
          const u16* vtp = Vt + (nb * 16 + fl) * 68 + i32 * 32 + 4 * g;
          short8 vf = mk8(*(const us4*)vtp, *(const us4*)(vtp + 16));
          oacc[nb] = __builtin_amdgcn_mfma_f32_16x16x32_bf16(pf, vf, oacc[nb], 0, 0, 0);
        }
      }
    }
    __syncthreads();
  }

  // finalize: divide by l (per q = 4g+r), store bf16
  float lr[4];
#pragma unroll
  for (int r = 0; r < 4; ++r) lr[r] = __shfl(lsum, 4 * g + r);
  const int orow0 = b * SEQ + qb * 64 + w * 16 + 4 * g;
#pragma unroll
  for (int nb = 0; nb < 4; ++nb) {
    int col = hh * DHEAD + nb * 16 + fl;
#pragma unroll
    for (int r = 0; r < 4; ++r)
      O[(size_t)(orow0 + r) * DMODEL + col] = f2bf(oacc[nb][r] / lr[r]);
  }
}

// ---------------- launcher ----------------
extern "C" void kernel_launch(void* const* d_in, const int* in_sizes, int n_in,
                              void* d_out, int out_size, void* d_ws, size_t ws_size,
                              hipStream_t stream) {
  const int*   x    = (const int*)d_in[0];
  const float* emb  = (const float*)d_in[1];
  const float* pos  = (const float*)d_in[2];
  const float* ln1g = (const float*)d_in[3];
  const float* ln1b = (const float*)d_in[4];
  const float* wq   = (const float*)d_in[5];
  const float* bq   = (const float*)d_in[6];
  const float* wk   = (const float*)d_in[7];
  const float* bk   = (const float*)d_in[8];
  const float* wv   = (const float*)d_in[9];
  const float* bv   = (const float*)d_in[10];
  const float* wo   = (const float*)d_in[11];
  const float* bo   = (const float*)d_in[12];
  const float* ln2g = (const float*)d_in[13];
  const float* ln2b = (const float*)d_in[14];
  const float* win  = (const float*)d_in[15];
  const float* bin  = (const float*)d_in[16];
  const float* wout = (const float*)d_in[17];
  const float* bout = (const float*)d_in[18];
  const float* lnfg = (const float*)d_in[19];
  const float* lnfb = (const float*)d_in[20];
  const float* outw = (const float*)d_in[21];

  char* w8 = (char*)d_ws;
  float* h   = (float*)(w8);               // 2048*768*4  = 6291456
  u16* abuf  = (u16*)(w8 + 6291456);       // 2048*768*2  = 3145728
  u16* qbuf  = (u16*)(w8 + 9437184);
  u16* kbuf  = (u16*)(w8 + 12582912);
  u16* vbuf  = (u16*)(w8 + 15728640);
  u16* obuf  = (u16*)(w8 + 18874368);      // ends at 22020096
  u16* ffbuf = qbuf;                       // alias: q/k/v/o dead when ff written

  k_embed<<<TKN, 256, 0, stream>>>(x, emb, pos, h);

  for (int l = 0; l < NL; ++l) {
    k_ln<<<TKN, 256, 0, stream>>>(h, ln1g + l * DMODEL, ln1b + l * DMODEL, abuf);
    k_gemm<0><<<dim3(DMODEL / BN, TKN / BM), 256, 0, stream>>>(
        abuf, wq + (size_t)l * DMODEL * DMODEL, bq + l * DMODEL, qbuf, DMODEL, DMODEL);
    k_gemm<0><<<dim3(DMODEL / BN, TKN / BM), 256, 0, stream>>>(
        abuf, wk + (size_t)l * DMODEL * DMODEL, bk + l * DMODEL, kbuf, DMODEL, DMODEL);
    k_gemm<0><<<dim3(DMODEL / BN, TKN / BM), 256, 0, stream>>>(
        abuf, wv + (size_t)l * DMODEL * DMODEL, bv + l * DMODEL, vbuf, DMODEL, DMODEL);
    k_attn<<<dim3(SEQ / 64, 2 * NH), 256, 0, stream>>>(qbuf, kbuf, vbuf, obuf);
    k_gemm<1><<<dim3(DMODEL / BN, TKN / BM), 256, 0, stream>>>(
        obuf, wo + (size_t)l * DMODEL * DMODEL, bo + l * DMODEL, h, DMODEL, DMODEL);
    k_ln<<<TKN, 256, 0, stream>>>(h, ln2g + l * DMODEL, ln2b + l * DMODEL, abuf);
    k_gemm<2><<<dim3(DFF / BN, TKN / BM), 256, 0, stream>>>(
        abuf, win + (size_t)l * DMODEL * DFF, bin + l * DFF, ffbuf, DFF, DMODEL);
    k_gemm<1><<<dim3(DMODEL / BN, TKN / BM), 256, 0, stream>>>(
        ffbuf, wout + (size_t)l * DFF * DMODEL, bout + l * DMODEL, h, DMODEL, DFF);
  }

  k_ln<<<TKN, 256, 0, stream>>>(h, lnfg, lnfb, abuf);
  k_gemm<3><<<dim3(NVOCAB / BN, TKN / BM), 256, 0, stream>>>(
      abuf, outw, nullptr, d_out, NVOCAB, DMODEL);
}